// Round 1
// baseline (213.341 us; speedup 1.0000x reference)
//
#include <hip/hip_runtime.h>
#include <math.h>

// Dims
#define LDIM 1024
#define BDIM 64
#define KDIM 512
#define VDIM 512
#define HDIM 8

// ---------------- init: write all biases / concat / zeros ----------------
__global__ void init_buffers(
    const float* __restrict__ til,     // [64,256]
    const float* __restrict__ b_state, // 256
    const float* __restrict__ bcq1, const float* __restrict__ bcq2,
    const float* __restrict__ bq,      // 4096
    const float* __restrict__ bagg,    // 512
    const float* __restrict__ brk1, const float* __restrict__ brk2,
    const float* __restrict__ brv1, const float* __restrict__ brv2,
    float* __restrict__ q0, float* __restrict__ q1, float* __restrict__ q2,
    float* __restrict__ qh, float* __restrict__ result, float* __restrict__ r,
    float* __restrict__ t1, float* __restrict__ t2, float* __restrict__ out)
{
    int stride = gridDim.x * blockDim.x;
    int tid = blockIdx.x * blockDim.x + threadIdx.x;
    for (int i = tid; i < 64*512; i += stride) {
        int c = i & 511;
        q0[i] = (c < 256) ? b_state[c] : til[(i >> 9)*256 + (c - 256)];
    }
    for (int i = tid; i < 64*512; i += stride) q1[i] = bcq1[i & 511];
    for (int i = tid; i < 64*512; i += stride) q2[i] = bcq2[i & 511];
    for (int i = tid; i < 64*4096; i += stride) qh[i] = bq[i & 4095];
    for (int i = tid; i < 64*4096; i += stride) result[i] = 0.f;
    for (int i = tid; i < 64*512; i += stride) r[i]  = bagg[i & 511];
    for (int i = tid; i < 64*512; i += stride) t1[i] = brk1[i & 511];
    for (int i = tid; i < 64*512; i += stride) t2[i] = brv1[i & 511];
    for (int i = tid; i < 64*512; i += stride) out[i] = brk2[i & 511];
    for (int i = tid; i < 64*512; i += stride) out[64*512 + i] = brv2[i & 511];
}

// ---------------- generic M=64 GEMM, atomic split-K accumulate ----------------
// C[m, ntile + n] += sum_k A[m,k] * W[k,n]; C pre-initialized with bias.
__global__ __launch_bounds__(256) void gemm64_atomic(
    const float* __restrict__ A, const float* __restrict__ W,
    float* __restrict__ C, int K, int N, int ldc, int kc)
{
    __shared__ float A_lds[16][64];   // [k][m]
    __shared__ float W_lds[16][64];   // [k][n]
    int tid = threadIdx.x;
    int tx = tid & 15;        // n-quad
    int ty = tid >> 4;        // m-quad
    int ntile = blockIdx.x * 64;
    int k0 = blockIdx.y * kc;
    float acc[4][4] = {};
    for (int kk = k0; kk < k0 + kc; kk += 16) {
        {   // stage A (transpose to [k][m])
            int row = tid >> 2;            // 0..63  (m)
            int kq  = (tid & 3) * 4;       // 0,4,8,12
            float4 v = *reinterpret_cast<const float4*>(&A[(size_t)row * K + kk + kq]);
            A_lds[kq+0][row] = v.x; A_lds[kq+1][row] = v.y;
            A_lds[kq+2][row] = v.z; A_lds[kq+3][row] = v.w;
        }
        {   // stage W directly [k][n]
            int wrow = tid >> 4;           // 0..15 (k)
            int wcol = (tid & 15) * 4;     // 0..60 (n)
            *reinterpret_cast<float4*>(&W_lds[wrow][wcol]) =
                *reinterpret_cast<const float4*>(&W[(size_t)(kk + wrow) * N + ntile + wcol]);
        }
        __syncthreads();
        #pragma unroll
        for (int k = 0; k < 16; ++k) {
            float4 a4 = *reinterpret_cast<const float4*>(&A_lds[k][ty*4]);
            float4 w4 = *reinterpret_cast<const float4*>(&W_lds[k][tx*4]);
            float a[4] = {a4.x, a4.y, a4.z, a4.w};
            float w[4] = {w4.x, w4.y, w4.z, w4.w};
            #pragma unroll
            for (int i = 0; i < 4; ++i)
                #pragma unroll
                for (int j = 0; j < 4; ++j)
                    acc[i][j] += a[i] * w[j];
        }
        __syncthreads();
    }
    #pragma unroll
    for (int i = 0; i < 4; ++i) {
        int m = ty*4 + i;
        #pragma unroll
        for (int j = 0; j < 4; ++j)
            atomicAdd(&C[(size_t)m * ldc + ntile + tx*4 + j], acc[i][j]);
    }
}

// ---------------- scores: scores[b,l,h] = rpe[l,b]/sqrt(K) * keys[l,b,:].q[b,h,:] ----------------
__global__ __launch_bounds__(256) void scores_kernel(
    const float* __restrict__ keys, const float* __restrict__ rpe,
    const float* __restrict__ qh, const int* __restrict__ step,
    float* __restrict__ scores)
{
    int b = blockIdx.y;
    int lc = blockIdx.x;
    int step_b = step[b];
    int l0 = lc * 64;
    if (l0 >= step_b) return;
    int lane = threadIdx.x & 63;
    int w = threadIdx.x >> 6;

    // q fragments: lane owns k in [lane*8, lane*8+8) for all 8 heads
    float qr[8][8];
    const float* qb = qh + (size_t)b * 4096 + lane * 8;
    #pragma unroll
    for (int h = 0; h < 8; ++h) {
        float4 x = *reinterpret_cast<const float4*>(&qb[h*512]);
        float4 y = *reinterpret_cast<const float4*>(&qb[h*512 + 4]);
        qr[h][0]=x.x; qr[h][1]=x.y; qr[h][2]=x.z; qr[h][3]=x.w;
        qr[h][4]=y.x; qr[h][5]=y.y; qr[h][6]=y.z; qr[h][7]=y.w;
    }
    int lend = min(l0 + 64, step_b);
    const float inv_sqrtK = 0.04419417382415922f; // 1/sqrt(512)
    for (int l = l0 + w; l < lend; l += 4) {
        const float* kp = keys + ((size_t)l * 64 + b) * 512 + lane * 8;
        float4 kx = *reinterpret_cast<const float4*>(kp);
        float4 ky = *reinterpret_cast<const float4*>(kp + 4);
        float kv[8] = {kx.x,kx.y,kx.z,kx.w, ky.x,ky.y,ky.z,ky.w};
        float p[8] = {};
        #pragma unroll
        for (int h = 0; h < 8; ++h)
            #pragma unroll
            for (int j = 0; j < 8; ++j)
                p[h] += kv[j] * qr[h][j];
        #pragma unroll
        for (int mask = 1; mask < 64; mask <<= 1) {
            #pragma unroll
            for (int h = 0; h < 8; ++h)
                p[h] += __shfl_xor(p[h], mask);
        }
        if (lane == 0) {
            float rp = rpe[l * 64 + b] * inv_sqrtK;
            float4 o1 = {p[0]*rp, p[1]*rp, p[2]*rp, p[3]*rp};
            float4 o2 = {p[4]*rp, p[5]*rp, p[6]*rp, p[7]*rp};
            float* sp = scores + ((size_t)b * 1024 + l) * 8;
            *reinterpret_cast<float4*>(sp) = o1;
            *reinterpret_cast<float4*>(sp + 4) = o2;
        }
    }
}

// ---------------- softmax over valid l per (b,h), in-place ----------------
__global__ __launch_bounds__(256) void softmax_kernel(
    float* __restrict__ scores, const int* __restrict__ step)
{
    int h = blockIdx.x, b = blockIdx.y;
    int step_b = step[b];
    int tid = threadIdx.x;
    float sv[4];
    float m = -1e30f;
    #pragma unroll
    for (int i = 0; i < 4; ++i) {
        int l = tid + i*256;
        if (l < step_b) { sv[i] = scores[((size_t)b*1024 + l)*8 + h]; m = fmaxf(m, sv[i]); }
        else sv[i] = -1e30f;
    }
    #pragma unroll
    for (int mask = 32; mask; mask >>= 1) m = fmaxf(m, __shfl_xor(m, mask));
    __shared__ float redm[4];
    if ((tid & 63) == 0) redm[tid >> 6] = m;
    __syncthreads();
    m = fmaxf(fmaxf(redm[0], redm[1]), fmaxf(redm[2], redm[3]));
    float s = 0.f;
    #pragma unroll
    for (int i = 0; i < 4; ++i) {
        int l = tid + i*256;
        if (l < step_b) { float e = expf(sv[i] - m); sv[i] = e; s += e; }
    }
    #pragma unroll
    for (int mask = 32; mask; mask >>= 1) s += __shfl_xor(s, mask);
    __shared__ float reds[4];
    if ((tid & 63) == 0) reds[tid >> 6] = s;
    __syncthreads();
    s = reds[0] + reds[1] + reds[2] + reds[3];
    float inv = 1.f / s;
    #pragma unroll
    for (int i = 0; i < 4; ++i) {
        int l = tid + i*256;
        if (l < step_b) scores[((size_t)b*1024 + l)*8 + h] = sv[i] * inv;
    }
}

// ---------------- PV: result[b, h*512+v] += sum_l prob[b,l,h] * vals[l,b,v] ----------------
__global__ __launch_bounds__(512) void pv_kernel(
    const float* __restrict__ vals, const float* __restrict__ prob,
    const int* __restrict__ step, float* __restrict__ result)
{
    int b = blockIdx.y, lc = blockIdx.x;
    int step_b = step[b];
    int l0 = lc * 128;
    if (l0 >= step_b) return;
    int nl = min(128, step_b - l0);
    __shared__ float p_lds[128*8];
    int tid = threadIdx.x;
    for (int i = tid; i < nl*8; i += 512)
        p_lds[i] = prob[((size_t)b*1024 + l0)*8 + i];
    __syncthreads();
    float acc[8] = {};
    for (int il = 0; il < nl; ++il) {
        float v = vals[(((size_t)(l0 + il))*64 + b)*512 + tid];
        float4 pa = *reinterpret_cast<const float4*>(&p_lds[il*8]);
        float4 pb = *reinterpret_cast<const float4*>(&p_lds[il*8 + 4]);
        acc[0] += pa.x*v; acc[1] += pa.y*v; acc[2] += pa.z*v; acc[3] += pa.w*v;
        acc[4] += pb.x*v; acc[5] += pb.y*v; acc[6] += pb.z*v; acc[7] += pb.w*v;
    }
    #pragma unroll
    for (int hh = 0; hh < 8; ++hh)
        atomicAdd(&result[(size_t)b*4096 + hh*512 + tid], acc[hh]);
}

// ---------------- launch ----------------
extern "C" void kernel_launch(void* const* d_in, const int* in_sizes, int n_in,
                              void* d_out, int out_size, void* d_ws, size_t ws_size,
                              hipStream_t stream) {
    const float* state   = (const float*)d_in[0];
    const float* til     = (const float*)d_in[1];
    const float* keys    = (const float*)d_in[2];
    const float* vals    = (const float*)d_in[3];
    const float* rpe     = (const float*)d_in[4];
    const int*   step    = (const int*)d_in[5];
    const float* W_state = (const float*)d_in[6];
    const float* b_state = (const float*)d_in[7];
    const float* Wcq1 = (const float*)d_in[8];
    const float* bcq1 = (const float*)d_in[9];
    const float* Wcq2 = (const float*)d_in[10];
    const float* bcq2 = (const float*)d_in[11];
    const float* Wq   = (const float*)d_in[12];
    const float* bq   = (const float*)d_in[13];
    const float* Wagg = (const float*)d_in[14];
    const float* bagg = (const float*)d_in[15];
    const float* Wrk1 = (const float*)d_in[16];
    const float* brk1 = (const float*)d_in[17];
    const float* Wrk2 = (const float*)d_in[18];
    const float* brk2 = (const float*)d_in[19];
    const float* Wrv1 = (const float*)d_in[20];
    const float* brv1 = (const float*)d_in[21];
    const float* Wrv2 = (const float*)d_in[22];
    const float* brv2 = (const float*)d_in[23];
    float* out = (float*)d_out;
    float* ws  = (float*)d_ws;

    float* q0     = ws;            // 64*512
    float* q1     = ws + 32768;    // 64*512
    float* q2     = ws + 65536;    // 64*512
    float* qh     = ws + 98304;    // 64*4096
    float* scores = ws + 360448;   // 64*1024*8 (also prob, in-place)
    float* result = ws + 884736;   // 64*4096
    float* r      = ws + 1146880;  // 64*512
    float* t1     = ws + 1179648;  // 64*512
    float* t2     = ws + 1212416;  // 64*512

    init_buffers<<<256, 256, 0, stream>>>(til, b_state, bcq1, bcq2, bq, bagg,
                                          brk1, brk2, brv1, brv2,
                                          q0, q1, q2, qh, result, r, t1, t2, out);
    // query chain
    gemm64_atomic<<<dim3(4, 8),  256, 0, stream>>>(state, W_state, q0, 512, 256, 512, 64);
    gemm64_atomic<<<dim3(8, 8),  256, 0, stream>>>(q0, Wcq1, q1, 512, 512, 512, 64);
    gemm64_atomic<<<dim3(8, 8),  256, 0, stream>>>(q1, Wcq2, q2, 512, 512, 512, 64);
    gemm64_atomic<<<dim3(64, 8), 256, 0, stream>>>(q2, Wq,   qh, 512, 4096, 4096, 64);
    // attention
    scores_kernel <<<dim3(16, 64), 256, 0, stream>>>(keys, rpe, qh, step, scores);
    softmax_kernel<<<dim3(8, 64),  256, 0, stream>>>(scores, step);
    pv_kernel     <<<dim3(8, 64),  512, 0, stream>>>(vals, scores, step, result);
    // output chain
    gemm64_atomic<<<dim3(8, 32), 256, 0, stream>>>(result, Wagg, r, 4096, 512, 512, 128);
    gemm64_atomic<<<dim3(8, 8),  256, 0, stream>>>(r,  Wrk1, t1, 512, 512, 512, 64);
    gemm64_atomic<<<dim3(8, 8),  256, 0, stream>>>(r,  Wrv1, t2, 512, 512, 512, 64);
    gemm64_atomic<<<dim3(8, 8),  256, 0, stream>>>(t1, Wrk2, out,        512, 512, 512, 64);
    gemm64_atomic<<<dim3(8, 8),  256, 0, stream>>>(t2, Wrv2, out + 32768, 512, 512, 512, 64);
}

// Round 2
// 197.781 us; speedup vs baseline: 1.0787x; 1.0787x over previous
//
#include <hip/hip_runtime.h>
#include <math.h>

#define F4(p)  (*reinterpret_cast<float4*>(p))
#define CF4(p) (*reinterpret_cast<const float4*>(p))

// ---------------- unified M=64 GEMM, split-K partial output ----------------
// P[(z*gridDim.y + s)][64][N] = A_eff @ W   (slice k in [s*kc, (s+1)*kc))
// MA=0: A_eff[m,k] = A[m*lda + k]
// MA=1: A_eff[m,k] = bA[k] + sum_t A[(t*64+m)*lda + k]
// MA=2: k<256: bias+partials (lda=256); k>=256: til[m*256 + k-256]
__global__ __launch_bounds__(256) void gemm64(
    const float* __restrict__ A0, const float* __restrict__ A1,
    const float* __restrict__ bA0, const float* __restrict__ bA1,
    const float* __restrict__ til,
    const float* __restrict__ W0, const float* __restrict__ W1,
    float* __restrict__ P,
    int lda, int SA, int N, int kc, int MA)
{
    __shared__ float A_lds[16][64];
    __shared__ float W_lds[16][64];
    const int tid = threadIdx.x;
    const int tx = tid & 15, ty = tid >> 4;
    const int ntile = blockIdx.x * 64;
    const int s = blockIdx.y, z = blockIdx.z;
    const int k0 = s * kc;
    const float* A  = z ? A1 : A0;
    const float* bA = z ? bA1 : bA0;
    const float* W  = z ? W1 : W0;
    const int row = tid >> 2, kq = (tid & 3) * 4;
    const int wrow = tid >> 4, wcol = (tid & 15) * 4;
    float acc[4][4] = {};
    for (int kk = k0; kk < k0 + kc; kk += 16) {
        const int kg = kk + kq;
        float4 av;
        if (MA == 0) {
            av = CF4(&A[(size_t)row * lda + kg]);
        } else if (MA == 1 || kg < 256) {
            av = CF4(&bA[kg]);
            for (int t = 0; t < SA; ++t) {
                float4 p4 = CF4(&A[((size_t)(t * 64) + row) * lda + kg]);
                av.x += p4.x; av.y += p4.y; av.z += p4.z; av.w += p4.w;
            }
        } else {
            av = CF4(&til[row * 256 + (kg - 256)]);
        }
        A_lds[kq+0][row] = av.x; A_lds[kq+1][row] = av.y;
        A_lds[kq+2][row] = av.z; A_lds[kq+3][row] = av.w;
        F4(&W_lds[wrow][wcol]) = CF4(&W[(size_t)(kk + wrow) * N + ntile + wcol]);
        __syncthreads();
        #pragma unroll
        for (int k = 0; k < 16; ++k) {
            float4 a4 = CF4(&A_lds[k][ty*4]);
            float4 w4 = CF4(&W_lds[k][tx*4]);
            float a[4] = {a4.x, a4.y, a4.z, a4.w};
            float w[4] = {w4.x, w4.y, w4.z, w4.w};
            #pragma unroll
            for (int i = 0; i < 4; ++i)
                #pragma unroll
                for (int j = 0; j < 4; ++j)
                    acc[i][j] += a[i] * w[j];
        }
        __syncthreads();
    }
    const size_t obase = (size_t)(z * gridDim.y + s) * 64;
    #pragma unroll
    for (int i = 0; i < 4; ++i) {
        float4 o = {acc[i][0], acc[i][1], acc[i][2], acc[i][3]};
        F4(&P[(obase + ty*4 + i) * N + ntile + tx*4]) = o;
    }
}

// ---------------- scores: scores[b,l,h] = rpe[l,b]/sqrt(K) * keys[l,b,:].q[b,h,:] ----------------
__global__ __launch_bounds__(256) void scores_kernel(
    const float* __restrict__ keys, const float* __restrict__ rpe,
    const float* __restrict__ P4, const float* __restrict__ bq,
    const int* __restrict__ step, float* __restrict__ scores)
{
    const int b = blockIdx.y, lc = blockIdx.x;
    const int step_b = step[b];
    const int l0 = lc * 64;
    if (l0 >= step_b) return;

    // stage q_eff[b] = bq + sum of 4 partials into LDS (16KB)
    __shared__ float q_lds[4096];
    for (int i = threadIdx.x; i < 1024; i += 256) {
        float4 v = CF4(&bq[i * 4]);
        #pragma unroll
        for (int t = 0; t < 4; ++t) {
            float4 p4 = CF4(&P4[((size_t)(t * 64) + b) * 4096 + i * 4]);
            v.x += p4.x; v.y += p4.y; v.z += p4.z; v.w += p4.w;
        }
        F4(&q_lds[i * 4]) = v;
    }
    __syncthreads();

    const int lane = threadIdx.x & 63, w = threadIdx.x >> 6;
    float qr[8][8];
    #pragma unroll
    for (int h = 0; h < 8; ++h) {
        float4 x = CF4(&q_lds[h * 512 + lane * 8]);
        float4 y = CF4(&q_lds[h * 512 + lane * 8 + 4]);
        qr[h][0]=x.x; qr[h][1]=x.y; qr[h][2]=x.z; qr[h][3]=x.w;
        qr[h][4]=y.x; qr[h][5]=y.y; qr[h][6]=y.z; qr[h][7]=y.w;
    }
    const int lend = min(l0 + 64, step_b);
    const float inv_sqrtK = 0.04419417382415922f; // 1/sqrt(512)
    const bool p0 = lane & 1, p1 = lane & 2, p2 = lane & 4;
    for (int l = l0 + w; l < lend; l += 4) {
        const float* kp = keys + ((size_t)l * 64 + b) * 512 + lane * 8;
        float4 kx = CF4(kp);
        float4 ky = CF4(kp + 4);
        float kv[8] = {kx.x,kx.y,kx.z,kx.w, ky.x,ky.y,ky.z,ky.w};
        float p[8] = {};
        #pragma unroll
        for (int h = 0; h < 8; ++h)
            #pragma unroll
            for (int j = 0; j < 8; ++j)
                p[h] += kv[j] * qr[h][j];
        // pair-combine multi-reduce: 8 values over 64 lanes -> head (lane&7)
        float w4[4], x2[2], y;
        #pragma unroll
        for (int i = 0; i < 4; ++i) {
            float keep = p0 ? p[2*i+1] : p[2*i];
            float send = p0 ? p[2*i]   : p[2*i+1];
            w4[i] = keep + __shfl_xor(send, 1);
        }
        #pragma unroll
        for (int i = 0; i < 2; ++i) {
            float keep = p1 ? w4[2*i+1] : w4[2*i];
            float send = p1 ? w4[2*i]   : w4[2*i+1];
            x2[i] = keep + __shfl_xor(send, 2);
        }
        {
            float keep = p2 ? x2[1] : x2[0];
            float send = p2 ? x2[0] : x2[1];
            y = keep + __shfl_xor(send, 4);
        }
        y += __shfl_xor(y, 8);
        y += __shfl_xor(y, 16);
        y += __shfl_xor(y, 32);
        if (lane < 8) {
            float rp = rpe[l * 64 + b] * inv_sqrtK;
            scores[((size_t)b * 1024 + l) * 8 + lane] = y * rp;
        }
    }
}

// ---------------- softmax over valid l per (b,h), in-place ----------------
__global__ __launch_bounds__(256) void softmax_kernel(
    float* __restrict__ scores, const int* __restrict__ step)
{
    int h = blockIdx.x, b = blockIdx.y;
    int step_b = step[b];
    int tid = threadIdx.x;
    float sv[4];
    float m = -1e30f;
    #pragma unroll
    for (int i = 0; i < 4; ++i) {
        int l = tid + i*256;
        if (l < step_b) { sv[i] = scores[((size_t)b*1024 + l)*8 + h]; m = fmaxf(m, sv[i]); }
        else sv[i] = -1e30f;
    }
    #pragma unroll
    for (int mask = 32; mask; mask >>= 1) m = fmaxf(m, __shfl_xor(m, mask));
    __shared__ float redm[4];
    if ((tid & 63) == 0) redm[tid >> 6] = m;
    __syncthreads();
    m = fmaxf(fmaxf(redm[0], redm[1]), fmaxf(redm[2], redm[3]));
    float s = 0.f;
    #pragma unroll
    for (int i = 0; i < 4; ++i) {
        int l = tid + i*256;
        if (l < step_b) { float e = expf(sv[i] - m); sv[i] = e; s += e; }
    }
    #pragma unroll
    for (int mask = 32; mask; mask >>= 1) s += __shfl_xor(s, mask);
    __shared__ float reds[4];
    if ((tid & 63) == 0) reds[tid >> 6] = s;
    __syncthreads();
    s = reds[0] + reds[1] + reds[2] + reds[3];
    float inv = 1.f / s;
    #pragma unroll
    for (int i = 0; i < 4; ++i) {
        int l = tid + i*256;
        if (l < step_b) scores[((size_t)b*1024 + l)*8 + h] = sv[i] * inv;
    }
}

// ---------------- PV partials: Ppv[lc][b][h*512+v] = sum_{l in chunk} prob*vals ----------------
__global__ __launch_bounds__(512) void pv_kernel(
    const float* __restrict__ vals, const float* __restrict__ prob,
    const int* __restrict__ step, float* __restrict__ Ppv)
{
    const int b = blockIdx.y, lc = blockIdx.x;
    const int step_b = step[b];
    const int l0 = lc * 128;
    const int tid = threadIdx.x;
    __shared__ float p_lds[128*8];
    float acc[8] = {};
    if (l0 < step_b) {
        const int nl = min(128, step_b - l0);
        for (int i = tid; i < nl*8; i += 512)
            p_lds[i] = prob[((size_t)b*1024 + l0)*8 + i];
        __syncthreads();
        for (int il = 0; il < nl; ++il) {
            float v = vals[(((size_t)(l0 + il))*64 + b)*512 + tid];
            float4 pa = CF4(&p_lds[il*8]);
            float4 pb = CF4(&p_lds[il*8 + 4]);
            acc[0] += pa.x*v; acc[1] += pa.y*v; acc[2] += pa.z*v; acc[3] += pa.w*v;
            acc[4] += pb.x*v; acc[5] += pb.y*v; acc[6] += pb.z*v; acc[7] += pb.w*v;
        }
    }
    #pragma unroll
    for (int hh = 0; hh < 8; ++hh)
        Ppv[((size_t)(lc * 64) + b) * 4096 + hh*512 + tid] = acc[hh];
}

// ---------------- reduce 8 PV partials -> result [64][4096] ----------------
__global__ __launch_bounds__(256) void reduce_result(
    const float* __restrict__ Ppv, float* __restrict__ result)
{
    int idx = (blockIdx.x * 256 + threadIdx.x) * 4;  // 65536 float4s
    float4 a = CF4(&Ppv[idx]);
    #pragma unroll
    for (int s = 1; s < 8; ++s) {
        float4 p = CF4(&Ppv[(size_t)s * 262144 + idx]);
        a.x += p.x; a.y += p.y; a.z += p.z; a.w += p.w;
    }
    F4(&result[idx]) = a;
}

// ---------------- reduce 4 out partials + bias -> out [2][64][512] ----------------
__global__ __launch_bounds__(256) void reduce_out(
    const float* __restrict__ P7, const float* __restrict__ brk2,
    const float* __restrict__ brv2, float* __restrict__ out)
{
    int idx = blockIdx.x * 256 + threadIdx.x;   // f4 index, 16384 total
    int z = idx >> 13, r = idx & 8191;
    int c4 = (r & 127) * 4;
    const float* bias = z ? brv2 : brk2;
    float4 a = CF4(&bias[c4]);
    #pragma unroll
    for (int s = 0; s < 4; ++s) {
        float4 p = CF4(&P7[((size_t)(z*4 + s) * 8192 + r) * 4]);
        a.x += p.x; a.y += p.y; a.z += p.z; a.w += p.w;
    }
    F4(&out[(size_t)idx * 4]) = a;
}

// ---------------- launch ----------------
extern "C" void kernel_launch(void* const* d_in, const int* in_sizes, int n_in,
                              void* d_out, int out_size, void* d_ws, size_t ws_size,
                              hipStream_t stream) {
    const float* state   = (const float*)d_in[0];
    const float* til     = (const float*)d_in[1];
    const float* keys    = (const float*)d_in[2];
    const float* vals    = (const float*)d_in[3];
    const float* rpe     = (const float*)d_in[4];
    const int*   step    = (const int*)d_in[5];
    const float* W_state = (const float*)d_in[6];
    const float* b_state = (const float*)d_in[7];
    const float* Wcq1 = (const float*)d_in[8];
    const float* bcq1 = (const float*)d_in[9];
    const float* Wcq2 = (const float*)d_in[10];
    const float* bcq2 = (const float*)d_in[11];
    const float* Wq   = (const float*)d_in[12];
    const float* bq   = (const float*)d_in[13];
    const float* Wagg = (const float*)d_in[14];
    const float* bagg = (const float*)d_in[15];
    const float* Wrk1 = (const float*)d_in[16];
    const float* brk1 = (const float*)d_in[17];
    const float* Wrk2 = (const float*)d_in[18];
    const float* brk2 = (const float*)d_in[19];
    const float* Wrv1 = (const float*)d_in[20];
    const float* brv1 = (const float*)d_in[21];
    const float* Wrv2 = (const float*)d_in[22];
    const float* brv2 = (const float*)d_in[23];
    float* out = (float*)d_out;
    float* ws  = (float*)d_ws;

    float* P1  = ws;            // [4][64][256]   65536
    float* P2  = ws + 65536;    // [4][64][512]   131072
    float* P3  = ws + 196608;   // [4][64][512]   131072
    float* P4  = ws + 327680;   // [4][64][4096]  1048576
    float* sc  = ws + 1376256;  // [64][1024][8]  524288
    float* Ppv = ws + 1900544;  // [8][64][4096]  2097152
    float* res = ws + 3997696;  // [64][4096]     262144
    float* P5  = ws + 4259840;  // [8][64][512]   262144
    float* P6  = ws + 4521984;  // [2][4][64][512] 262144
    float* P7  = ws + 4784128;  // [2][4][64][512] 262144

    // query chain
    gemm64<<<dim3(4,4,1),  256, 0, stream>>>(state, state, state, state, nullptr,
                                             W_state, W_state, P1, 512, 0, 256, 128, 0);
    gemm64<<<dim3(8,4,1),  256, 0, stream>>>(P1, P1, b_state, b_state, til,
                                             Wcq1, Wcq1, P2, 256, 4, 512, 128, 2);
    gemm64<<<dim3(8,4,1),  256, 0, stream>>>(P2, P2, bcq1, bcq1, nullptr,
                                             Wcq2, Wcq2, P3, 512, 4, 512, 128, 1);
    gemm64<<<dim3(64,4,1), 256, 0, stream>>>(P3, P3, bcq2, bcq2, nullptr,
                                             Wq, Wq, P4, 512, 4, 4096, 128, 1);
    // attention
    scores_kernel <<<dim3(16,64), 256, 0, stream>>>(keys, rpe, P4, bq, step, sc);
    softmax_kernel<<<dim3(8,64),  256, 0, stream>>>(sc, step);
    pv_kernel     <<<dim3(8,64),  512, 0, stream>>>(vals, sc, step, Ppv);
    reduce_result <<<256, 256, 0, stream>>>(Ppv, res);
    // output chain
    gemm64<<<dim3(8,8,1),  256, 0, stream>>>(res, res, nullptr, nullptr, nullptr,
                                             Wagg, Wagg, P5, 4096, 0, 512, 512, 0);
    gemm64<<<dim3(8,4,2),  256, 0, stream>>>(P5, P5, bagg, bagg, nullptr,
                                             Wrk1, Wrv1, P6, 512, 8, 512, 128, 1);
    gemm64<<<dim3(8,4,2),  256, 0, stream>>>(P6, P6 + 131072, brk1, brv1, nullptr,
                                             Wrk2, Wrv2, P7, 512, 4, 512, 128, 1);
    reduce_out<<<64, 256, 0, stream>>>(P7, brk2, brv2, out);
}